// Round 14
// baseline (367.319 us; speedup 1.0000x reference)
//
#include <hip/hip_runtime.h>
#include <hip/hip_bf16.h>
#include <float.h>

#define BB 512
#define TT 40
#define CC 512
#define HH 512

typedef short bf16x8 __attribute__((ext_vector_type(8)));
typedef float f32x4 __attribute__((ext_vector_type(4)));
typedef unsigned short ushortx8 __attribute__((ext_vector_type(8)));

// LDS map (bytes): Wih panel [48][1024B] | Whh panel [48][1024B] | arrive
#define LDSH 49152
#define LDSF 98304
#define LDSTOT 98320

__device__ __forceinline__ unsigned short f2bf(float f){
  union { float f; unsigned int i; } v; v.f = f;
  unsigned int r = v.i + 0x7fffu + ((v.i >> 16) & 1u);
  return (unsigned short)(r >> 16);
}

// 16B global load, L1-bypass (h produced by other CUs)
__device__ __forceinline__ bf16x8 load_sc0(const unsigned short* p){
  bf16x8 r;
  asm volatile("global_load_dwordx4 %0, %1, off sc0" : "=v"(r) : "v"(p));
  return r;
}
// 16B global load, normal path (read-only x)
__device__ __forceinline__ bf16x8 load_g(const unsigned short* p){
  bf16x8 r;
  asm volatile("global_load_dwordx4 %0, %1, off" : "=v"(r) : "v"(p));
  return r;
}
#define WAITV(N) do { asm volatile("s_waitcnt vmcnt(" #N ")" ::: "memory"); \
                      __builtin_amdgcn_sched_barrier(0); } while(0)

__device__ __forceinline__ void waitv_idx(int n){
  switch(n){
    case 0:  WAITV(0);  break;  case 1:  WAITV(1);  break;
    case 2:  WAITV(2);  break;  case 3:  WAITV(3);  break;
    case 4:  WAITV(4);  break;  case 5:  WAITV(5);  break;
    case 6:  WAITV(6);  break;  case 7:  WAITV(7);  break;
    case 8:  WAITV(8);  break;  case 9:  WAITV(9);  break;
    case 10: WAITV(10); break;  case 11: WAITV(11); break;
    case 12: WAITV(12); break;  case 13: WAITV(13); break;
    case 14: WAITV(14); break;  default: WAITV(15); break;
  }
}

__device__ __forceinline__ float fast_sigmoid(float x){
  return __builtin_amdgcn_rcpf(1.f + __expf(-x));
}
__device__ __forceinline__ float fast_tanh(float x){
  return 1.f - 2.f*__builtin_amdgcn_rcpf(__expf(2.f*x) + 1.f);
}

// one wave per (b,t): convert 512 floats -> bf16, compute nonzero mask (transposed [T][B])
__global__ void prep_x_kernel(const float* __restrict__ x, unsigned short* __restrict__ xb,
                              float* __restrict__ maskT){
  int w = blockIdx.x*4 + (threadIdx.x>>6);
  int lane = threadIdx.x & 63;
  const float* src = x + (size_t)w*CC + lane*8;
  f32x4 a = *(const f32x4*)(src);
  f32x4 b = *(const f32x4*)(src+4);
  ushortx8 o;
  o[0]=f2bf(a[0]); o[1]=f2bf(a[1]); o[2]=f2bf(a[2]); o[3]=f2bf(a[3]);
  o[4]=f2bf(b[0]); o[5]=f2bf(b[1]); o[6]=f2bf(b[2]); o[7]=f2bf(b[3]);
  *(ushortx8*)(xb + (size_t)w*CC + lane*8) = o;
  bool nz = (a[0]!=0.f)||(a[1]!=0.f)||(a[2]!=0.f)||(a[3]!=0.f)||
            (b[0]!=0.f)||(b[1]!=0.f)||(b[2]!=0.f)||(b[3]!=0.f);
  unsigned long long bal = __ballot(nz);
  if (lane==0){
    int b_ = w / TT, t_ = w % TT;
    maskT[t_*BB + b_] = bal ? 1.0f : 0.0f;
  }
}

__global__ void cvt_kernel(const float* __restrict__ src, unsigned short* __restrict__ dst, int n8){
  int i = blockIdx.x*blockDim.x + threadIdx.x;
  if (i < n8){
    f32x4 a = *(const f32x4*)(src + i*8);
    f32x4 b = *(const f32x4*)(src + i*8 + 4);
    ushortx8 o;
    o[0]=f2bf(a[0]); o[1]=f2bf(a[1]); o[2]=f2bf(a[2]); o[3]=f2bf(a[3]);
    o[4]=f2bf(b[0]); o[5]=f2bf(b[1]); o[6]=f2bf(b[2]); o[7]=f2bf(b[3]);
    *(ushortx8*)(dst + i*8) = o;
  }
}

// zero bf16 h buffers and the spread flag array (256 flags, 128B apart)
__global__ void init_h_kernel(unsigned short* __restrict__ hb, unsigned int* __restrict__ flags){
  int i = blockIdx.x*blockDim.x + threadIdx.x;
  hb[i] = 0;
  if (i < 256) flags[i*32] = 0u;
}

// Persistent GRU, 256 WGs x 512 threads (8 waves), 1 WG/CU, grp = bid&7 -> XCD.
// R8 skeleton + contention fixes: per-strip flags on SEPARATE 128B lines
// (poll lanes 0-31 each hit a different line; publish stores uncontended),
// s_sleep(4) poll backoff, depth-16 asm pipelining for BOTH x and h loads,
// publish moved before max-pool bookkeeping.
__global__ __launch_bounds__(512, 2) void gru_persist_kernel(
    const unsigned short* __restrict__ xb,
    const unsigned short* __restrict__ wihF, const unsigned short* __restrict__ whhF,
    const unsigned short* __restrict__ wihB, const unsigned short* __restrict__ whhB,
    const float* __restrict__ bihF, const float* __restrict__ bhhF,
    const float* __restrict__ bihB, const float* __restrict__ bhhB,
    const float* __restrict__ maskT,
    unsigned short* __restrict__ hb,
    float* __restrict__ out, unsigned int* __restrict__ flags)
{
  const int bid   = blockIdx.x;
  const int grp   = bid & 7;       // XCD-local group (round-robin dispatch)
  const int strip = bid >> 3;      // 0..31
  const int dir   = grp >> 2;
  const int bslab = grp & 3;
  const int b0 = bslab * 128;
  const int n0 = strip * 16;
  // this group's 32 flags, each on its own 128B line
  unsigned int* fl = flags + (size_t)grp*32*32;

  const unsigned short* wih = dir ? wihB : wihF;
  const unsigned short* whh = dir ? whhB : whhF;
  const float* bih = dir ? bihB : bihF;
  const float* bhh = dir ? bhhB : bhhF;

  const int tid  = threadIdx.x;
  const int lane = tid & 63;
  const int lr   = lane & 15;
  const int lkg  = lane >> 4;
  const int wv   = tid >> 6;        // 0..7
  const int wrow = wv * 16;

  __shared__ __align__(16) char smem[LDSTOT];
  unsigned int* arrive = (unsigned int*)(smem + LDSF);

  // ---- stage weights: Wih panel + Whh panel, [48 rows][1024B], swizzled
  for (int q = tid; q < 6144; q += 512) {
    const int p_  = q >= 3072;
    const int r_  = p_ ? (q - 3072) : q;
    const int row = r_ >> 6;                  // 0..47 (gate*16 + col)
    const int kc  = (r_ & 63) * 8;            // 0..504
    const unsigned short* src =
        (p_ ? whh : wih) + ((size_t)((row>>4)*HH + n0 + (row&15)))*512 + kc;
    *(ushortx8*)(smem + p_*LDSH + row*1024 + ((kc*2) ^ ((row&15)<<4))) =
        *(const ushortx8*)src;
  }
  if (tid == 0) arrive[0] = 0u;
  __syncthreads();   // the only workgroup barrier

  const int jj = n0 + lr;
  const float br  = bih[jj]        + bhh[jj];
  const float bz  = bih[HH + jj]   + bhh[HH + jj];
  const float bnx = bih[2*HH + jj];
  const float bnh = bhh[2*HH + jj];

  float omax[4], hreg[4];
  #pragma unroll
  for (int j=0; j<4; ++j){ omax[j] = -FLT_MAX; hreg[j] = 0.f; }

  const int swz = lr << 4;
  const char* wbx = smem + lr*1024;          // Wih panel row for col jj
  const char* wbh = smem + LDSH + lr*1024;   // Whh panel row for col jj

  for (int t = 0; t < TT; ++t) {
    const int tx = dir ? (TT-1-t) : t;
    const int bi = t & 1;
    const unsigned short* hbin = hb + (size_t)(dir*2 + bi)      * (BB*HH);
    unsigned short* hbout      = hb + (size_t)(dir*2 + (bi^1))  * (BB*HH);

    f32x4 ar = 0.f, az = 0.f, anx = 0.f, anh = 0.f;

    const unsigned short* xr0 = xb + ((size_t)(b0 + wrow + lr)*TT + tx)*CC;

    // ---- x-part (K=0..511): depth-16 asm loads (cross-XCD L2, one RTT)
    bf16x8 px[16];
    #pragma unroll
    for (int q = 0; q < 16; ++q)
      px[q] = load_g(xr0 + q*32 + lkg*8);
    #pragma unroll
    for (int kk = 0; kk < 16; ++kk) {
      const int ko = kk*32 + lkg*8;
      const int kbx = (ko*2) ^ swz;
      bf16x8 brf = *(const bf16x8*)(wbx +         kbx);
      bf16x8 bzf = *(const bf16x8*)(wbx + 16384 + kbx);
      bf16x8 bnf = *(const bf16x8*)(wbx + 32768 + kbx);
      waitv_idx(15 - kk);
      bf16x8 a0 = px[kk];
      ar  = __builtin_amdgcn_mfma_f32_16x16x32_bf16(a0, brf, ar,0,0,0);
      az  = __builtin_amdgcn_mfma_f32_16x16x32_bf16(a0, bzf, az,0,0,0);
      anx = __builtin_amdgcn_mfma_f32_16x16x32_bf16(a0, bnf, anx,0,0,0);
    }

    // ---- mask load (no chain dependency)
    const f32x4 mk = *(const f32x4*)(maskT + tx*BB + b0 + wrow + lkg*4);

    // ---- wait for step t's h: lanes 0-31 each poll a DIFFERENT 128B line
    if (t > 0) {
      const unsigned int tgt = (unsigned)t;
      unsigned int spin = 0;
      for (;;) {
        unsigned int v = tgt;
        if (lane < 32)
          v = __hip_atomic_load(&fl[lane*32], __ATOMIC_RELAXED, __HIP_MEMORY_SCOPE_AGENT);
        if (__ballot(v < tgt) == 0ull) break;
        if (++spin >= (1u<<24)) break;
        __builtin_amdgcn_s_sleep(4);
      }
    }
    WAITV(0);   // drain mask/flag loads so the h vmcnt countdown is exact

    // ---- h-part (K=0..511 of Whh): depth-16 sc0 loads, exact countdown
    const unsigned short* hr0 = hbin + (size_t)(b0 + wrow + lr)*HH;
    bf16x8 ph[16];
    #pragma unroll
    for (int q = 0; q < 16; ++q)
      ph[q] = load_sc0(hr0 + q*32 + lkg*8);
    #pragma unroll
    for (int kk = 0; kk < 16; ++kk) {
      const int ko = kk*32 + lkg*8;
      const int kbx = (ko*2) ^ swz;
      bf16x8 brf = *(const bf16x8*)(wbh +         kbx);
      bf16x8 bzf = *(const bf16x8*)(wbh + 16384 + kbx);
      bf16x8 bnf = *(const bf16x8*)(wbh + 32768 + kbx);
      waitv_idx(15 - kk);
      bf16x8 c0 = ph[kk];
      ar  = __builtin_amdgcn_mfma_f32_16x16x32_bf16(c0, brf, ar,0,0,0);
      az  = __builtin_amdgcn_mfma_f32_16x16x32_bf16(c0, bzf, az,0,0,0);
      anh = __builtin_amdgcn_mfma_f32_16x16x32_bf16(c0, bnf, anh,0,0,0);
    }

    // ---- gates + h store FIRST (publish ASAP), bookkeeping after
    float hn4[4];
    #pragma unroll
    for (int j=0; j<4; ++j){
      const int b = b0 + wrow + lkg*4 + j;
      const float rg = fast_sigmoid(ar[j] + br);
      const float zg = fast_sigmoid(az[j] + bz);
      const float ng = fast_tanh(anx[j] + bnx + rg*(anh[j] + bnh));
      const float hn = (1.f - zg)*ng + zg*hreg[j];
      hreg[j] = hn;
      hn4[j] = hn;
      hbout[(size_t)b*HH + jj] = f2bf(hn);
    }

    // publish: drain own h-stores; last-arriving wave stores the strip's flag
    if (t < TT-1) {
      WAITV(0);
      if (lane == 0) {
        unsigned int prev =
            __hip_atomic_fetch_add(arrive, 1u, __ATOMIC_ACQ_REL, __HIP_MEMORY_SCOPE_WORKGROUP);
        if (prev + 1u == 8u*(unsigned)(t+1))
          __hip_atomic_store(&fl[strip*32], (unsigned)(t+1),
                             __ATOMIC_RELAXED, __HIP_MEMORY_SCOPE_AGENT);
      }
    }

    // max-pool bookkeeping (off the chain)
    #pragma unroll
    for (int j=0; j<4; ++j){
      const float cand = (mk[j] != 0.f) ? hn4[j] : -FLT_MAX;
      omax[j] = fmaxf(omax[j], cand);
    }
  }

  // ---- final masked-max write: out[b][dir*H + jj]
  #pragma unroll
  for (int j=0; j<4; ++j){
    const int b = b0 + wrow + lkg*4 + j;
    out[(size_t)b*(2*HH) + dir*HH + jj] = omax[j];
  }
}

extern "C" void kernel_launch(void* const* d_in, const int* in_sizes, int n_in,
                              void* d_out, int out_size, void* d_ws, size_t ws_size,
                              hipStream_t stream) {
  const float* x    = (const float*)d_in[0];
  const float* WihF = (const float*)d_in[1];
  const float* WhhF = (const float*)d_in[2];
  const float* bihF = (const float*)d_in[3];
  const float* bhhF = (const float*)d_in[4];
  const float* WihB = (const float*)d_in[5];
  const float* WhhB = (const float*)d_in[6];
  const float* bihB = (const float*)d_in[7];
  const float* bhhB = (const float*)d_in[8];
  float* out = (float*)d_out;

  char* ws = (char*)d_ws;
  unsigned short* xb    = (unsigned short*)(ws);              // B*T*C bf16
  unsigned short* wb    = (unsigned short*)(ws + 20971520);
  unsigned short* wihFb = wb;
  unsigned short* whhFb = wb + 786432;
  unsigned short* wihBb = wb + 2*786432;
  unsigned short* whhBb = wb + 3*786432;
  float* maskT = (float*)(ws + 27262976);                     // [T][B]
  unsigned short* hb = (unsigned short*)(ws + 27344896);      // [2dir][2buf][B][H] bf16
  unsigned int* flags = (unsigned int*)(ws + 29442048);       // 256 flags x 128B

  prep_x_kernel<<<BB*TT/4, 256, 0, stream>>>(x, xb, maskT);
  cvt_kernel<<<384, 256, 0, stream>>>(WihF, wihFb, 98304);
  cvt_kernel<<<384, 256, 0, stream>>>(WhhF, whhFb, 98304);
  cvt_kernel<<<384, 256, 0, stream>>>(WihB, wihBb, 98304);
  cvt_kernel<<<384, 256, 0, stream>>>(WhhB, whhBb, 98304);
  init_h_kernel<<<4096, 256, 0, stream>>>(hb, flags);

  gru_persist_kernel<<<256, 512, 0, stream>>>(xb, wihFb, whhFb, wihBb, whhBb,
                                              bihF, bhhF, bihB, bhhB,
                                              maskT, hb, out, flags);
}

// Round 15
// 336.021 us; speedup vs baseline: 1.0931x; 1.0931x over previous
//
#include <hip/hip_runtime.h>
#include <hip/hip_bf16.h>
#include <float.h>

#define BB 512
#define TT 40
#define CC 512
#define HH 512

typedef short bf16x8 __attribute__((ext_vector_type(8)));
typedef float f32x4 __attribute__((ext_vector_type(4)));
typedef unsigned short ushortx8 __attribute__((ext_vector_type(8)));

// LDS map (bytes): x-panel [48][1024B] | h-panel [48][1024B] | arrive counter
#define LDSH 49152
#define LDSF 98304
#define LDSTOT 98320

__device__ __forceinline__ unsigned short f2bf(float f){
  union { float f; unsigned int i; } v; v.f = f;
  unsigned int r = v.i + 0x7fffu + ((v.i >> 16) & 1u);
  return (unsigned short)(r >> 16);
}

__device__ __forceinline__ bf16x8 load_sc0(const unsigned short* p){
  bf16x8 r;
  asm volatile("global_load_dwordx4 %0, %1, off sc0" : "=v"(r) : "v"(p));
  return r;
}
#define WAITV(N) do { asm volatile("s_waitcnt vmcnt(" #N ")" ::: "memory"); \
                      __builtin_amdgcn_sched_barrier(0); } while(0)

__device__ __forceinline__ float fast_sigmoid(float x){
  return __builtin_amdgcn_rcpf(1.f + __expf(-x));
}
__device__ __forceinline__ float fast_tanh(float x){
  return 1.f - 2.f*__builtin_amdgcn_rcpf(__expf(2.f*x) + 1.f);
}

// one wave per (b,t): convert 512 floats -> bf16, compute nonzero mask (transposed [T][B])
__global__ void prep_x_kernel(const float* __restrict__ x, unsigned short* __restrict__ xb,
                              float* __restrict__ maskT){
  int w = blockIdx.x*4 + (threadIdx.x>>6);
  int lane = threadIdx.x & 63;
  const float* src = x + (size_t)w*CC + lane*8;
  f32x4 a = *(const f32x4*)(src);
  f32x4 b = *(const f32x4*)(src+4);
  ushortx8 o;
  o[0]=f2bf(a[0]); o[1]=f2bf(a[1]); o[2]=f2bf(a[2]); o[3]=f2bf(a[3]);
  o[4]=f2bf(b[0]); o[5]=f2bf(b[1]); o[6]=f2bf(b[2]); o[7]=f2bf(b[3]);
  *(ushortx8*)(xb + (size_t)w*CC + lane*8) = o;
  bool nz = (a[0]!=0.f)||(a[1]!=0.f)||(a[2]!=0.f)||(a[3]!=0.f)||
            (b[0]!=0.f)||(b[1]!=0.f)||(b[2]!=0.f)||(b[3]!=0.f);
  unsigned long long bal = __ballot(nz);
  if (lane==0){
    int b_ = w / TT, t_ = w % TT;
    maskT[t_*BB + b_] = bal ? 1.0f : 0.0f;
  }
}

// vectorized f32 -> bf16 weight convert (8 elems/thread)
__global__ void cvt_kernel(const float* __restrict__ src, unsigned short* __restrict__ dst, int n8){
  int i = blockIdx.x*blockDim.x + threadIdx.x;
  if (i < n8){
    f32x4 a = *(const f32x4*)(src + i*8);
    f32x4 b = *(const f32x4*)(src + i*8 + 4);
    ushortx8 o;
    o[0]=f2bf(a[0]); o[1]=f2bf(a[1]); o[2]=f2bf(a[2]); o[3]=f2bf(a[3]);
    o[4]=f2bf(b[0]); o[5]=f2bf(b[1]); o[6]=f2bf(b[2]); o[7]=f2bf(b[3]);
    *(ushortx8*)(dst + i*8) = o;
  }
}

__global__ void init_h_kernel(unsigned short* __restrict__ hb, unsigned int* __restrict__ ctr){
  int i = blockIdx.x*blockDim.x + threadIdx.x;
  hb[i] = 0;
  if (i < 8) ctr[i*32] = 0u;
}

// Persistent GRU, 256 WGs x 512 threads (8 waves), 1 WG/CU, 2 waves/SIMD.
// [R8 configuration — empirical best of the session at 335 us.]
// Each wave owns 16 rows x 16 cols and runs the full x-part -> poll -> h-part
// -> epilogue pipeline independently; two waves per SIMD give TLP so one
// wave's stalls hide under the other's MFMAs. Sync: all waves direct-poll the
// group counter (wave-uniform address, one hop); publish via LDS arrive
// counter -> single global add per WG per step (32 adders/group).
__global__ __launch_bounds__(512, 2) void gru_persist_kernel(
    const unsigned short* __restrict__ xb,
    const unsigned short* __restrict__ wihF, const unsigned short* __restrict__ whhF,
    const unsigned short* __restrict__ wihB, const unsigned short* __restrict__ whhB,
    const float* __restrict__ bihF, const float* __restrict__ bhhF,
    const float* __restrict__ bihB, const float* __restrict__ bhhB,
    const float* __restrict__ maskT,
    unsigned short* __restrict__ hb,
    float* __restrict__ out, unsigned int* __restrict__ ctr)
{
  const int bid   = blockIdx.x;
  const int grp   = bid & 7;       // XCD-local group (round-robin dispatch)
  const int strip = bid >> 3;      // 0..31
  const int dir   = grp >> 2;
  const int bslab = grp & 3;
  const int b0 = bslab * 128;
  const int n0 = strip * 16;
  unsigned int* myctr = ctr + grp*32;

  const unsigned short* wih = dir ? wihB : wihF;
  const unsigned short* whh = dir ? whhB : whhF;
  const float* bih = dir ? bihB : bihF;
  const float* bhh = dir ? bhhB : bhhF;

  const int tid  = threadIdx.x;
  const int lane = tid & 63;
  const int lr   = lane & 15;
  const int lkg  = lane >> 4;
  const int wv   = tid >> 6;        // 0..7
  const int wrow = wv * 16;         // wave's 16-row slice

  __shared__ __align__(16) char smem[LDSTOT];
  unsigned int* arrive = (unsigned int*)(smem + LDSF);

  // ---- stage weights: x-panel + h-panel, [48 rows][1024B], row = gate*16+col,
  //      byte offset (kc*2) ^ ((row&15)<<4)  (conflict-free reads)
  for (int q = tid; q < 6144; q += 512) {
    const int p_  = q >= 3072;
    const int r_  = p_ ? (q - 3072) : q;
    const int row = r_ >> 6;                  // 0..47
    const int kc  = (r_ & 63) * 8;            // 0..504
    const unsigned short* src =
        (p_ ? whh : wih) + ((size_t)((row>>4)*HH + n0 + (row&15)))*512 + kc;
    *(ushortx8*)(smem + p_*LDSH + row*1024 + ((kc*2) ^ ((row&15)<<4))) =
        *(const ushortx8*)src;
  }
  if (tid == 0) arrive[0] = 0u;
  __syncthreads();   // the only workgroup barrier

  const int jj = n0 + lr;
  const float br  = bih[jj]        + bhh[jj];
  const float bz  = bih[HH + jj]   + bhh[HH + jj];
  const float bnx = bih[2*HH + jj];
  const float bnh = bhh[2*HH + jj];

  float omax[4], hreg[4];
  #pragma unroll
  for (int j=0; j<4; ++j){ omax[j] = -FLT_MAX; hreg[j] = 0.f; }

  const int swz = lr << 4;
  const char* wbx = smem + lr*1024;          // x-panel row for col jj
  const char* wbh = smem + LDSH + lr*1024;   // h-panel row for col jj

  for (int t = 0; t < TT; ++t) {
    const int tx = dir ? (TT-1-t) : t;
    const int bi = t & 1;
    const unsigned short* hbin = hb + (size_t)(dir*2 + bi)      * (BB*HH);
    unsigned short* hbout      = hb + (size_t)(dir*2 + (bi^1))  * (BB*HH);

    f32x4 ar = 0.f, az = 0.f, anx = 0.f, anh = 0.f;

    const unsigned short* xr0 = xb + ((size_t)(b0 + wrow + lr)*TT + tx)*CC;

    // ---- x-part (K=0..511): no h dependency; absorbs inter-WG skew
    #pragma unroll
    for (int kk = 0; kk < 16; ++kk) {
      const int ko = kk*32 + lkg*8;
      bf16x8 a0 = *(const bf16x8*)(xr0 + ko);
      const int kbx = (ko*2) ^ swz;
      bf16x8 brf = *(const bf16x8*)(wbx +         kbx);
      bf16x8 bzf = *(const bf16x8*)(wbx + 16384 + kbx);
      bf16x8 bnf = *(const bf16x8*)(wbx + 32768 + kbx);
      ar  = __builtin_amdgcn_mfma_f32_16x16x32_bf16(a0, brf, ar,0,0,0);
      az  = __builtin_amdgcn_mfma_f32_16x16x32_bf16(a0, bzf, az,0,0,0);
      anx = __builtin_amdgcn_mfma_f32_16x16x32_bf16(a0, bnf, anx,0,0,0);
    }

    // ---- mask load (no h dependency)
    const f32x4 mk = *(const f32x4*)(maskT + tx*BB + b0 + wrow + lkg*4);

    // ---- direct wait for step t's h (wave-uniform poll, one hop)
    if (t > 0) {
      const unsigned int tgt = 32u*(unsigned)t;
      unsigned int spin = 0;
      while (__hip_atomic_load(myctr, __ATOMIC_RELAXED, __HIP_MEMORY_SCOPE_AGENT) < tgt
             && ++spin < (1u<<24))
        __builtin_amdgcn_s_sleep(1);
    }

    WAITV(0);   // drain x/mask loads so h-pipeline vmcnt counting is exact

    // ---- h-part (K=0..511 of Whh): depth-4 pipelined sc0 loads, 1 load/kk
    const unsigned short* hr0 = hbin + (size_t)(b0 + wrow + lr)*HH;
    bf16x8 ph[4];
    #pragma unroll
    for (int q = 0; q < 4; ++q)
      ph[q] = load_sc0(hr0 + q*32 + lkg*8);
    #pragma unroll
    for (int kk = 0; kk < 16; ++kk) {
      const int ko = kk*32 + lkg*8;
      const int kbx = (ko*2) ^ swz;
      bf16x8 brf = *(const bf16x8*)(wbh +         kbx);
      bf16x8 bzf = *(const bf16x8*)(wbh + 16384 + kbx);
      bf16x8 bnf = *(const bf16x8*)(wbh + 32768 + kbx);
      if (kk < 13)      { WAITV(3); }
      else if (kk == 13){ WAITV(2); }
      else if (kk == 14){ WAITV(1); }
      else              { WAITV(0); }
      bf16x8 c0 = ph[kk&3];
      ar  = __builtin_amdgcn_mfma_f32_16x16x32_bf16(c0, brf, ar,0,0,0);
      az  = __builtin_amdgcn_mfma_f32_16x16x32_bf16(c0, bzf, az,0,0,0);
      anh = __builtin_amdgcn_mfma_f32_16x16x32_bf16(c0, bnf, anh,0,0,0);
      if (kk < 12)
        ph[kk&3] = load_sc0(hr0 + (kk+4)*32 + lkg*8);
    }

    // ---- epilogue: gates, register h carry, register max-pool
    #pragma unroll
    for (int j=0; j<4; ++j){
      const int b = b0 + wrow + lkg*4 + j;
      const float rg = fast_sigmoid(ar[j] + br);
      const float zg = fast_sigmoid(az[j] + bz);
      const float ng = fast_tanh(anx[j] + bnx + rg*(anh[j] + bnh));
      const float hn = (1.f - zg)*ng + zg*hreg[j];
      hreg[j] = hn;
      hbout[(size_t)b*HH + jj] = f2bf(hn);
      const float cand = (mk[j] != 0.f) ? hn : -FLT_MAX;
      omax[j] = fmaxf(omax[j], cand);
    }

    // ---- publish: per-wave drain -> LDS arrive; wave0 waits arrive==8*(t+1),
    //      does the single global add for this WG
    if (t < TT-1) {
      WAITV(0);   // own h stores drained to L2
      if (lane == 0)
        __hip_atomic_fetch_add(arrive, 1u, __ATOMIC_RELEASE, __HIP_MEMORY_SCOPE_WORKGROUP);
      if (wv == 0 && lane == 0) {
        const unsigned int tgt = 8u*(unsigned)(t+1);
        unsigned int spin = 0;
        while (__hip_atomic_load(arrive, __ATOMIC_ACQUIRE, __HIP_MEMORY_SCOPE_WORKGROUP) < tgt
               && ++spin < (1u<<24))
          __builtin_amdgcn_s_sleep(1);
        __hip_atomic_fetch_add(myctr, 1u, __ATOMIC_RELAXED, __HIP_MEMORY_SCOPE_AGENT);
      }
    }
  }

  // ---- final masked-max write: out[b][dir*H + jj]
  #pragma unroll
  for (int j=0; j<4; ++j){
    const int b = b0 + wrow + lkg*4 + j;
    out[(size_t)b*(2*HH) + dir*HH + jj] = omax[j];
  }
}

extern "C" void kernel_launch(void* const* d_in, const int* in_sizes, int n_in,
                              void* d_out, int out_size, void* d_ws, size_t ws_size,
                              hipStream_t stream) {
  const float* x    = (const float*)d_in[0];
  const float* WihF = (const float*)d_in[1];
  const float* WhhF = (const float*)d_in[2];
  const float* bihF = (const float*)d_in[3];
  const float* bhhF = (const float*)d_in[4];
  const float* WihB = (const float*)d_in[5];
  const float* WhhB = (const float*)d_in[6];
  const float* bihB = (const float*)d_in[7];
  const float* bhhB = (const float*)d_in[8];
  float* out = (float*)d_out;

  char* ws = (char*)d_ws;
  unsigned short* xb    = (unsigned short*)(ws);              // B*T*C bf16
  unsigned short* wb    = (unsigned short*)(ws + 20971520);
  unsigned short* wihFb = wb;
  unsigned short* whhFb = wb + 786432;
  unsigned short* wihBb = wb + 2*786432;
  unsigned short* whhBb = wb + 3*786432;
  float* maskT = (float*)(ws + 27262976);                     // [T][B]
  unsigned short* hb = (unsigned short*)(ws + 27344896);      // [2dir][2buf][B][H] bf16
  unsigned int* ctr  = (unsigned int*)(ws + 29442048);        // 8 counters, 128B stride

  prep_x_kernel<<<BB*TT/4, 256, 0, stream>>>(x, xb, maskT);
  cvt_kernel<<<384, 256, 0, stream>>>(WihF, wihFb, 98304);
  cvt_kernel<<<384, 256, 0, stream>>>(WhhF, whhFb, 98304);
  cvt_kernel<<<384, 256, 0, stream>>>(WihB, wihBb, 98304);
  cvt_kernel<<<384, 256, 0, stream>>>(WhhB, whhBb, 98304);
  init_h_kernel<<<4096, 256, 0, stream>>>(hb, ctr);

  gru_persist_kernel<<<256, 512, 0, stream>>>(xb, wihFb, whhFb, wihBb, whhBb,
                                              bihF, bhhF, bihB, bhhB,
                                              maskT, hb, out, ctr);
}